// Round 13
// baseline (271.857 us; speedup 1.0000x reference)
//
#include <hip/hip_runtime.h>
#include <hip/hip_bf16.h>
#include <math.h>

// PosNetEncoder: B=2, I=J=1024, D=1024, H=16, DH=64, K=64 (R=129), FF=4096
#define D_   1024
#define H_   16
#define DH_  64
#define FF_  4096
#define R_   129
#define I_   1024
#define B_   2
#define MROWS 2048   // B_*I_
#define QKVLD 3072   // merged q1|k|q2 row stride

typedef __bf16 v8bf16 __attribute__((ext_vector_type(8)));
typedef float f32x4 __attribute__((ext_vector_type(4)));

__device__ __forceinline__ float gelu_f(float x) {
    return 0.5f * x * (1.0f + erff(x * 0.7071067811865476f));
}

__device__ __forceinline__ void ldsld16(const void* g, void* l) {
    __builtin_amdgcn_global_load_lds(
        (const __attribute__((address_space(1))) void*)g,
        (__attribute__((address_space(3))) void*)l, 16, 0, 0);
}

// ---------------- fp32 -> bf16 convert (vector-4) ---------------------------
__global__ __launch_bounds__(256) void cvt_bf16(const float* __restrict__ in,
        __hip_bfloat16* __restrict__ out, int n4) {
    int i = blockIdx.x * 256 + threadIdx.x;
    if (i >= n4) return;
    float4 v = reinterpret_cast<const float4*>(in)[i];
    union { __hip_bfloat16 h[4]; uint2 u; } pk;
    pk.h[0] = __float2bfloat16(v.x); pk.h[1] = __float2bfloat16(v.y);
    pk.h[2] = __float2bfloat16(v.z); pk.h[3] = __float2bfloat16(v.w);
    reinterpret_cast<uint2*>(out)[i] = pk.u;
}

// ---- rel cvt (blocks 0..128) + bias concat copies (blocks 129..133) --------
__global__ __launch_bounds__(256) void cvt_rel_bias(const float* __restrict__ rel,
        __hip_bfloat16* __restrict__ relb,
        const float* __restrict__ q1b_, const float* __restrict__ kb_,
        const float* __restrict__ q2b_, const float* __restrict__ vb_,
        const float* __restrict__ gb_,
        float* __restrict__ bias3, float* __restrict__ bias2) {
    int bid = blockIdx.x, t = threadIdx.x;
    if (bid < 129) {
        int i = bid * 256 + t;
        float4 v = reinterpret_cast<const float4*>(rel)[i];
        union { __hip_bfloat16 h[4]; uint2 u; } pk;
        pk.h[0] = __float2bfloat16(v.x); pk.h[1] = __float2bfloat16(v.y);
        pk.h[2] = __float2bfloat16(v.z); pk.h[3] = __float2bfloat16(v.w);
        reinterpret_cast<uint2*>(relb)[i] = pk.u;
    } else {
        int k = bid - 129;   // 0..4 -> q1,k,q2 (bias3) ; v,g (bias2)
        const float* src = k == 0 ? q1b_ : k == 1 ? kb_ : k == 2 ? q2b_ : k == 3 ? vb_ : gb_;
        float* dst = (k < 3 ? bias3 + k * D_ : bias2 + (k - 3) * D_);
        reinterpret_cast<float4*>(dst)[t] = reinterpret_cast<const float4*>(src)[t];
    }
}

// ------ 6x batched D_xD_ transpose (one dispatch, z selects weight) ---------
__global__ __launch_bounds__(256) void wtrans6(
        const float* __restrict__ s0, const float* __restrict__ s1,
        const float* __restrict__ s2, const float* __restrict__ s3,
        const float* __restrict__ s4, const float* __restrict__ s5,
        __hip_bfloat16* __restrict__ d0, __hip_bfloat16* __restrict__ d1,
        __hip_bfloat16* __restrict__ d2, __hip_bfloat16* __restrict__ d3,
        __hip_bfloat16* __restrict__ d4, __hip_bfloat16* __restrict__ d5) {
    __shared__ float T[64][65];
    int z = blockIdx.z;
    const float* W = z == 0 ? s0 : z == 1 ? s1 : z == 2 ? s2 : z == 3 ? s3 : z == 4 ? s4 : s5;
    __hip_bfloat16* WT = z == 0 ? d0 : z == 1 ? d1 : z == 2 ? d2 : z == 3 ? d3 : z == 4 ? d4 : d5;
    int k0 = blockIdx.y * 64, n0 = blockIdx.x * 64;
    int t = threadIdx.x;
#pragma unroll
    for (int i = 0; i < 16; i++) {
        int e = t + i * 256, r = e >> 6, c = e & 63;
        T[r][c] = W[(size_t)(k0 + r) * D_ + n0 + c];
    }
    __syncthreads();
#pragma unroll
    for (int i = 0; i < 16; i++) {
        int e = t + i * 256, r = e >> 6, c = e & 63;
        WT[(size_t)(n0 + r) * D_ + k0 + c] = __float2bfloat16(T[c][r]);
    }
}

// ------ ff1 + ff2 transposes in one dispatch (z=0: ff1, z=1: ff2) -----------
__global__ __launch_bounds__(256) void wtrans_ff(
        const float* __restrict__ f1, const float* __restrict__ f2,
        __hip_bfloat16* __restrict__ d1, __hip_bfloat16* __restrict__ d2) {
    __shared__ float T[64][65];
    int z = blockIdx.z;
    const float* W = z == 0 ? f1 : f2;
    __hip_bfloat16* WT = z == 0 ? d1 : d2;
    int K = z == 0 ? D_ : FF_;
    int N = z == 0 ? FF_ : D_;
    int k0 = (z == 0 ? blockIdx.y : blockIdx.x) * 64;
    int n0 = (z == 0 ? blockIdx.x : blockIdx.y) * 64;
    int t = threadIdx.x;
#pragma unroll
    for (int i = 0; i < 16; i++) {
        int e = t + i * 256, r = e >> 6, c = e & 63;
        T[r][c] = W[(size_t)(k0 + r) * N + n0 + c];
    }
    __syncthreads();
#pragma unroll
    for (int i = 0; i < 16; i++) {
        int e = t + i * 256, r = e >> 6, c = e & 63;
        WT[(size_t)(n0 + r) * K + k0 + c] = __float2bfloat16(T[c][r]);
    }
}

// ---- v[b,j,h,d] fp32 -> vt[b,h,d,j] bf16 (64x64 tiles) ---------------------
__global__ __launch_bounds__(256) void vtrans(const float* __restrict__ v,
        __hip_bfloat16* __restrict__ vt) {
    __shared__ float T[64][65];
    int z = blockIdx.y, b = z >> 4, h = z & 15;
    int j0 = blockIdx.x * 64;
    int t = threadIdx.x;
#pragma unroll
    for (int i = 0; i < 16; i++) {
        int e = t + i * 256, r = e >> 6, c = e & 63;   // r=j, c=d
        T[r][c] = v[(size_t)(b * I_ + j0 + r) * D_ + h * DH_ + c];
    }
    __syncthreads();
#pragma unroll
    for (int i = 0; i < 16; i++) {
        int e = t + i * 256, r = e >> 6, c = e & 63;   // r=d, c=j
        vt[((size_t)z * DH_ + r) * I_ + j0 + c] = __float2bfloat16(T[c][r]);
    }
}

// ---------------- MFMA bf16 GEMM: C = epi(A[M,K] @ Bt[N,K]^T) ---------------
// Tile BM = (4/NWC)*MR*16 x BN = NWC*64, 4 waves, 16x16x32 MFMA.
// OUTBF: 0 f32 out, 1 bf16 out, 2 split (col<D_ -> f32 Cout, else bf16 via res).
template<int MR, int NWC, int ACT, int RES, int OUTBF>
__global__ __launch_bounds__(256) void gemm_mfma(
        const __hip_bfloat16* __restrict__ A,
        const __hip_bfloat16* __restrict__ Bt,
        const float* __restrict__ bias,
        const float* __restrict__ res,
        void* __restrict__ Cout,
        int N, int Kd, int lda, int ldb, int ldc,
        size_t sAb, size_t sAh, size_t sBb, size_t sBh, size_t sCz) {
    constexpr int NWR = 4 / NWC;
    constexpr int BM = NWR * MR * 16;
    constexpr int BN = NWC * 64;
    __shared__ __align__(16) __hip_bfloat16 As[BM * 64];
    __shared__ __align__(16) __hip_bfloat16 Bs[BN * 64];
    const char* AsB = (const char*)As;
    const char* BsB = (const char*)Bs;
    int z = blockIdx.z;
    const __hip_bfloat16* Ab = A + (size_t)(z >> 4) * sAb + (size_t)(z & 15) * sAh;
    const __hip_bfloat16* Bb = Bt + (size_t)(z >> 4) * sBb + (size_t)(z & 15) * sBh;
    float* Cf = (float*)Cout + (size_t)z * sCz;
    __hip_bfloat16* Cb = (__hip_bfloat16*)Cout + (size_t)z * sCz;
    int m0 = blockIdx.y * BM, n0 = blockIdx.x * BN;
    int t = threadIdx.x;
    int l = t & 63, w = t >> 6;
    int wr = w / NWC, wc = w % NWC;
    int lr = l & 15, kq = l >> 4;
    int rx = lr & 7;

    f32x4 acc[MR][4] = {};

    for (int k0 = 0; k0 < Kd; k0 += 64) {
#pragma unroll
        for (int i = 0; i < BM / 32; i++) {
            int e = t + i * 256;
            int row = e >> 3, sl = e & 7;
            int kb = sl ^ (row & 7);
            ldsld16(Ab + (size_t)(m0 + row) * lda + (k0 + kb * 8), (void*)(AsB + e * 16));
        }
#pragma unroll
        for (int i = 0; i < BN / 32; i++) {
            int e = t + i * 256;
            int row = e >> 3, sl = e & 7;
            int kb = sl ^ (row & 7);
            int nr = n0 + row; if (nr > N - 1) nr = N - 1;   // tail tile (arf N=129)
            ldsld16(Bb + (size_t)nr * ldb + (k0 + kb * 8), (void*)(BsB + e * 16));
        }
        __syncthreads();
#pragma unroll
        for (int kc = 0; kc < 2; kc++) {
            int sloff = (((kc << 2) + kq) ^ rx) << 4;
            v8bf16 af[MR], bfr[4];
#pragma unroll
            for (int mr = 0; mr < MR; mr++)
                af[mr] = *(const v8bf16*)(AsB + ((wr * (MR * 16) + mr * 16 + lr) << 7) + sloff);
#pragma unroll
            for (int nc = 0; nc < 4; nc++)
                bfr[nc] = *(const v8bf16*)(BsB + ((wc * 64 + nc * 16 + lr) << 7) + sloff);
#pragma unroll
            for (int mr = 0; mr < MR; mr++)
#pragma unroll
                for (int nc = 0; nc < 4; nc++)
                    acc[mr][nc] = __builtin_amdgcn_mfma_f32_16x16x32_bf16(
                        af[mr], bfr[nc], acc[mr][nc], 0, 0, 0);
        }
        __syncthreads();
    }

#pragma unroll
    for (int mr = 0; mr < MR; mr++) {
        int rbase = m0 + wr * (MR * 16) + mr * 16 + kq * 4;
#pragma unroll
        for (int nc = 0; nc < 4; nc++) {
            int col = n0 + wc * 64 + nc * 16 + lr;
            bool okc = col < N;
            float bv = (bias && okc) ? bias[col] : 0.f;
#pragma unroll
            for (int ri = 0; ri < 4; ri++) {
                int r = rbase + ri;
                float val = acc[mr][nc][ri] + bv;
                if (ACT == 1) val = gelu_f(val);
                if (ACT == 2) val = fmaxf(val, 0.f);
                if (RES) val += res[(size_t)r * ldc + col];
                if (okc) {
                    if (OUTBF == 2) {
                        if (col < D_) Cf[(size_t)r * ldc + col] = val;
                        else ((__hip_bfloat16*)res)[(size_t)r * ldc + (col - D_)] =
                                 __float2bfloat16(val);
                    } else if (OUTBF == 1) {
                        Cb[(size_t)r * ldc + col] = __float2bfloat16(val);
                    } else {
                        Cf[(size_t)r * ldc + col] = val;
                    }
                }
            }
        }
    }
}

// ---------------- fused attention, two-pass flash, KVBLK=128 pairs ----------
// Block = 64 q-rows x one (b,h); 4 waves; wave w owns rows w*16..w*16+15.
// K/V tiles processed in PAIRS: stage 2 tiles -> 1 sync -> compute both ->
// 1 sync. Barrier-drain events halved vs R8 (passA 32->16, passB 48->24).
// arf gather reads global (L2-resident 33KB slice) -> LDS stays 48KB,
// occupancy 3 blocks/CU (unchanged vs R8).
// LDS: K pair 16384 | V pair 16384 | P pair (Q staged in half 0) 16384
#define F6_K  0
#define F6_V  16384
#define F6_P  32768
#define SC2   0.1803368801111244f     // 0.125 * log2(e)
__global__ __launch_bounds__(256) void flash_attn6(
        const __hip_bfloat16* __restrict__ qkv,
        const __hip_bfloat16* __restrict__ vt,
        const __hip_bfloat16* __restrict__ arfb,
        const __hip_bfloat16* __restrict__ gb,
        float* __restrict__ a_out,
        __hip_bfloat16* __restrict__ obuf) {
    __shared__ __align__(16) char lds[49152];
    char* kB = lds + F6_K;
    char* vB = lds + F6_V;
    char* pB = lds + F6_P;

    int z = blockIdx.y, b = z >> 4, h = z & 15;
    int i0 = blockIdx.x * 64;
    int t = threadIdx.x, l = t & 63, w = t >> 6;
    int lr = l & 15, kq = l >> 4;
    const __hip_bfloat16* Kg = qkv + (size_t)(b * I_) * QKVLD + D_ + h * DH_;
    const __hip_bfloat16* Vg = vt + (size_t)z * DH_ * I_;
    const __hip_bfloat16* arz = arfb + (size_t)z * I_ * R_;

    // stage Q (64 rows x 64 d, swizzled) into pB half 0
#pragma unroll
    for (int i = 0; i < 2; i++) {
        int e = t + i * 256;
        int row = e >> 3, sl = e & 7;
        int kb = sl ^ (row & 7);
        ldsld16(qkv + (size_t)(b * I_ + i0 + row) * QKVLD + h * DH_ + kb * 8,
                (void*)(pB + e * 16));
    }
    __syncthreads();
    v8bf16 qf[2];
#pragma unroll
    for (int kc = 0; kc < 2; kc++)
        qf[kc] = *(const v8bf16*)(pB + ((w * 16 + lr) << 7) + ((((kc << 2) + kq) ^ (lr & 7)) << 4));

    int irow = w * 16 + kq * 4;      // lane's first row within 64
    int ig = i0 + irow;              // global i for ri=0
    float loS[4], hiS[4];
#pragma unroll
    for (int ri = 0; ri < 4; ri++) {
        loS[ri] = __bfloat162float(arz[((size_t)(ig + ri)) * R_ + 0])   * SC2;
        hiS[ri] = __bfloat162float(arz[((size_t)(ig + ri)) * R_ + 128]) * SC2;
    }

    // ---- pass A: per-lane l = sum exp2(s2), tiles in pairs ----------------
    float l_ln[4] = {0.f, 0.f, 0.f, 0.f};
    for (int jp = 0; jp < 8; jp++) {
#pragma unroll
        for (int hf = 0; hf < 2; hf++) {
#pragma unroll
            for (int i = 0; i < 2; i++) {
                int e = t + i * 256;
                int row = e >> 3, sl = e & 7;
                int kb = sl ^ (row & 7);
                ldsld16(Kg + (size_t)((jp * 2 + hf) * 64 + row) * QKVLD + kb * 8,
                        (void*)(kB + hf * 8192 + e * 16));
            }
        }
        __syncthreads();
#pragma unroll
        for (int hf = 0; hf < 2; hf++) {
            int j0 = (jp * 2 + hf) * 64;
            const char* kBh = kB + hf * 8192;
            f32x4 acc[4] = {};
            __builtin_amdgcn_s_setprio(1);
#pragma unroll
            for (int kc = 0; kc < 2; kc++) {
                int sloff = ((((kc << 2) + kq)) ^ (lr & 7)) << 4;
#pragma unroll
                for (int tt = 0; tt < 4; tt++) {
                    v8bf16 kf = *(const v8bf16*)(kBh + ((tt * 16 + lr) << 7) + sloff);
                    acc[tt] = __builtin_amdgcn_mfma_f32_16x16x32_bf16(qf[kc], kf, acc[tt], 0, 0, 0);
                }
            }
            __builtin_amdgcn_s_setprio(0);
#pragma unroll
            for (int ri = 0; ri < 4; ri++) {
                int i_g = ig + ri;
                float sc[4];
                bool lo_all = (j0 + 63) <= (i_g - 64);
                bool hi_all = j0 >= (i_g + 64);
                if (lo_all || hi_all) {
                    float c = lo_all ? loS[ri] : hiS[ri];
#pragma unroll
                    for (int tt = 0; tt < 4; tt++) sc[tt] = fmaf(acc[tt][ri], SC2, c);
                } else {
#pragma unroll
                    for (int tt = 0; tt < 4; tt++) {
                        int reln = j0 + tt * 16 + lr - i_g;
                        float arv = reln <= -64 ? loS[ri] : (reln >= 64 ? hiS[ri] :
                            __bfloat162float(arz[(size_t)i_g * R_ + reln + 64]) * SC2);
                        sc[tt] = fmaf(acc[tt][ri], SC2, arv);
                    }
                }
                l_ln[ri] += exp2f(sc[0]) + exp2f(sc[1]) + exp2f(sc[2]) + exp2f(sc[3]);
            }
        }
        __syncthreads();
    }
    float offb[4];
#pragma unroll
    for (int ri = 0; ri < 4; ri++) {
        float s = l_ln[ri];
#pragma unroll
        for (int off = 1; off < 16; off <<= 1) s += __shfl_xor(s, off, 64);
        offb[ri] = __log2f(s);
    }

    // ---- pass B: p = exp2(s2 - log2 l); a_out (nontemporal); PV, pairs ----
    f32x4 oacc[4] = {};
    for (int jp = 0; jp < 8; jp++) {
#pragma unroll
        for (int hf = 0; hf < 2; hf++) {
#pragma unroll
            for (int i = 0; i < 2; i++) {
                int e = t + i * 256;
                int row = e >> 3, sl = e & 7;
                int kb = sl ^ (row & 7);
                ldsld16(Kg + (size_t)((jp * 2 + hf) * 64 + row) * QKVLD + kb * 8,
                        (void*)(kB + hf * 8192 + e * 16));
                ldsld16(Vg + (size_t)row * I_ + (jp * 2 + hf) * 64 + kb * 8,
                        (void*)(vB + hf * 8192 + e * 16));
            }
        }
        __syncthreads();
#pragma unroll
        for (int hf = 0; hf < 2; hf++) {
            int j0 = (jp * 2 + hf) * 64;
            const char* kBh = kB + hf * 8192;
            char* pBh = pB + hf * 8192;
            f32x4 acc[4] = {};
            __builtin_amdgcn_s_setprio(1);
#pragma unroll
            for (int kc = 0; kc < 2; kc++) {
                int sloff = ((((kc << 2) + kq)) ^ (lr & 7)) << 4;
#pragma unroll
                for (int tt = 0; tt < 4; tt++) {
                    v8bf16 kf = *(const v8bf16*)(kBh + ((tt * 16 + lr) << 7) + sloff);
                    acc[tt] = __builtin_amdgcn_mfma_f32_16x16x32_bf16(qf[kc], kf, acc[tt], 0, 0, 0);
                }
            }
            __builtin_amdgcn_s_setprio(0);
#pragma unroll
            for (int ri = 0; ri < 4; ri++) {
                int i_g = ig + ri;
                int rowl = irow + ri;
                float sc[4];
                bool lo_all = (j0 + 63) <= (i_g - 64);
                bool hi_all = j0 >= (i_g + 64);
                if (lo_all || hi_all) {
                    float c = lo_all ? loS[ri] : hiS[ri];
#pragma unroll
                    for (int tt = 0; tt < 4; tt++) sc[tt] = fmaf(acc[tt][ri], SC2, c);
                } else {
#pragma unroll
                    for (int tt = 0; tt < 4; tt++) {
                        int reln = j0 + tt * 16 + lr - i_g;
                        float arv = reln <= -64 ? loS[ri] : (reln >= 64 ? hiS[ri] :
                            __bfloat162float(arz[(size_t)i_g * R_ + reln + 64]) * SC2);
                        sc[tt] = fmaf(acc[tt][ri], SC2, arv);
                    }
                }
                float* gout = a_out + ((size_t)z * I_ + i0 + rowl) * I_ + j0;
#pragma unroll
                for (int tt = 0; tt < 4; tt++) {
                    float p = exp2f(sc[tt] - offb[ri]);
                    __builtin_nontemporal_store(p, gout + tt * 16 + lr);
                    *(__hip_bfloat16*)(pBh + (rowl << 7) +
                            ((((tt * 2) + (lr >> 3)) ^ (rowl & 7)) << 4) + (lr & 7) * 2) =
                        __float2bfloat16(p);
                }
            }
        }
        __syncthreads();
        __builtin_amdgcn_s_setprio(1);
#pragma unroll
        for (int hf = 0; hf < 2; hf++) {
#pragma unroll
            for (int kc = 0; kc < 2; kc++) {
                int sloff = ((((kc << 2) + kq)) ^ (lr & 7)) << 4;
                v8bf16 pf = *(const v8bf16*)(pB + hf * 8192 + ((w * 16 + lr) << 7) + sloff);
#pragma unroll
                for (int nc = 0; nc < 4; nc++) {
                    v8bf16 vf = *(const v8bf16*)(vB + hf * 8192 + ((nc * 16 + lr) << 7) + sloff);
                    oacc[nc] = __builtin_amdgcn_mfma_f32_16x16x32_bf16(pf, vf, oacc[nc], 0, 0, 0);
                }
            }
        }
        __builtin_amdgcn_s_setprio(0);
        __syncthreads();
    }
#pragma unroll
    for (int nc = 0; nc < 4; nc++) {
#pragma unroll
        for (int ri = 0; ri < 4; ri++) {
            int r = i0 + irow + ri;
            size_t oi = ((size_t)(b * I_ + r)) * D_ + h * DH_ + nc * 16 + lr;
            obuf[oi] = __float2bfloat16(oacc[nc][ri] * __bfloat162float(gb[oi]));
        }
    }
}

// ---------------- LayerNorm rows of 1024 (256 thr, float4) ------------------
template<int OUTBF>
__global__ __launch_bounds__(256) void ln_kernel(const float* __restrict__ in,
        void* __restrict__ out, const float* __restrict__ gw,
        const float* __restrict__ bw) {
    __shared__ float shs[4], shq[4];
    int row = blockIdx.x;
    int t = threadIdx.x;
    float4 v = reinterpret_cast<const float4*>(in + (size_t)row * D_)[t];
    float s = v.x + v.y + v.z + v.w;
#pragma unroll
    for (int off = 32; off > 0; off >>= 1) s += __shfl_down(s, off, 64);
    if ((t & 63) == 0) shs[t >> 6] = s;
    __syncthreads();
    float mean = (shs[0] + shs[1] + shs[2] + shs[3]) * (1.0f / D_);
    float d0 = v.x - mean, d1 = v.y - mean, d2 = v.z - mean, d3 = v.w - mean;
    float q = d0 * d0 + d1 * d1 + d2 * d2 + d3 * d3;
#pragma unroll
    for (int off = 32; off > 0; off >>= 1) q += __shfl_down(q, off, 64);
    if ((t & 63) == 0) shq[t >> 6] = q;
    __syncthreads();
    float var = (shq[0] + shq[1] + shq[2] + shq[3]) * (1.0f / D_);
    float rstd = rsqrtf(var + 1e-5f);
    float4 g4 = reinterpret_cast<const float4*>(gw)[t];
    float4 b4 = reinterpret_cast<const float4*>(bw)[t];
    float o0 = d0 * rstd * g4.x + b4.x;
    float o1 = d1 * rstd * g4.y + b4.y;
    float o2 = d2 * rstd * g4.z + b4.z;
    float o3 = d3 * rstd * g4.w + b4.w;
    if (OUTBF) {
        union { __hip_bfloat16 h[4]; uint2 u; } pk;
        pk.h[0] = __float2bfloat16(o0); pk.h[1] = __float2bfloat16(o1);
        pk.h[2] = __float2bfloat16(o2); pk.h[3] = __float2bfloat16(o3);
        reinterpret_cast<uint2*>((__hip_bfloat16*)out + (size_t)row * D_)[t] = pk.u;
    } else {
        float4 o; o.x = o0; o.y = o1; o.z = o2; o.w = o3;
        reinterpret_cast<float4*>((float*)out + (size_t)row * D_)[t] = o;
    }
}

extern "C" void kernel_launch(void* const* d_in, const int* in_sizes, int n_in,
                              void* d_out, int out_size, void* d_ws, size_t ws_size,
                              hipStream_t stream) {
    const float* x      = (const float*)d_in[0];
    const float* jin    = (const float*)d_in[1];
    const float* ln1_g  = (const float*)d_in[2];
    const float* ln1_b  = (const float*)d_in[3];
    const float* Wv_w   = (const float*)d_in[4];
    const float* Wv_b   = (const float*)d_in[5];
    const float* Wg_w   = (const float*)d_in[6];
    const float* Wg_b   = (const float*)d_in[7];
    const float* lnv_g  = (const float*)d_in[8];
    const float* lnv_b  = (const float*)d_in[9];
    const float* Wq1_w  = (const float*)d_in[10];
    const float* Wq1_b  = (const float*)d_in[11];
    const float* Wk_w   = (const float*)d_in[12];
    const float* Wk_b   = (const float*)d_in[13];
    const float* Wq2_w  = (const float*)d_in[14];
    const float* Wq2_b  = (const float*)d_in[15];
    const float* rel    = (const float*)d_in[16];
    const float* Wo_w   = (const float*)d_in[17];
    const float* Wo_b   = (const float*)d_in[18];
    const float* ln2_g  = (const float*)d_in[19];
    const float* ln2_b  = (const float*)d_in[20];
    const float* ff1_w  = (const float*)d_in[21];
    const float* ff1_b  = (const float*)d_in[22];
    const float* ff2_w  = (const float*)d_in[23];
    const float* ff2_b  = (const float*)d_in[24];
    // d_in[25] = indices: computed analytically on device

    float* out0  = (float*)d_out;
    float* a_out = out0 + (size_t)B_ * I_ * D_;    // [B,H,I,J]

    char* wsb = (char*)d_ws;
    const size_t MB = 1u << 20;
    // persistent bf16 transposed weights [0,28MB)
    __hip_bfloat16* wvwgT= (__hip_bfloat16*)(wsb + 0 * MB);   // [2048,1024] 4MB
    __hip_bfloat16* qkvT = (__hip_bfloat16*)(wsb + 4 * MB);   // [3072,1024] 6MB
    __hip_bfloat16* WoT  = (__hip_bfloat16*)(wsb + 10 * MB);
    __hip_bfloat16* ff1T = (__hip_bfloat16*)(wsb + 12 * MB);  // [4096,1024] 8MB
    __hip_bfloat16* ff2T = (__hip_bfloat16*)(wsb + 20 * MB);  // [1024,4096] 8MB
    // activations, slot-reused along the timeline
    __hip_bfloat16* jbf  = (__hip_bfloat16*)(wsb + 28 * MB);  // dead after qkv GEMM
    __hip_bfloat16* qkv  = (__hip_bfloat16*)(wsb + 32 * MB);  // [2048,3072] 12MB, live->flash
    __hip_bfloat16* relb = (__hip_bfloat16*)(wsb + 44 * MB);  // 0.26MB, dead after arf
    __hip_bfloat16* arfb = (__hip_bfloat16*)(wsb + 45 * MB);  // 8.06MB, live->flash
    __hip_bfloat16* gbuf = (__hip_bfloat16*)(wsb + 54 * MB);  // 4MB, live->flash
    float*          vbuf = (float*)        (wsb + 58 * MB);   // 8MB f32, dead after vtrans
    __hip_bfloat16* xnb  = (__hip_bfloat16*)(wsb + 28 * MB);  // reuse jbf (dead after WvWg)
    __hip_bfloat16* vt   = (__hip_bfloat16*)(wsb + 28 * MB);  // reuse xnb, live->flash
    __hip_bfloat16* obuf = (__hip_bfloat16*)(wsb + 58 * MB);  // reuse vbuf (dead)
    float*          x1   = (float*)        (wsb + 32 * MB);   // reuse qkv (dead after flash)
    __hip_bfloat16* x1nb = (__hip_bfloat16*)(wsb + 40 * MB);  // reuse qkv tail (dead)
    __hip_bfloat16* hbuf = (__hip_bfloat16*)(wsb + 44 * MB);  // 16MB, 44-60 (all dead)
    float*          bias3= (float*)        (wsb + 66 * MB);   // [3072] f32 concat
    float*          bias2= (float*)        (wsb + 66 * MB + 16384);  // [2048] f32 concat

    dim3 blk(256);

    // prologue: 4 dispatches
    cvt_bf16<<<2048, blk, 0, stream>>>(jin, jbf, (MROWS * D_) / 4);
    cvt_rel_bias<<<134, blk, 0, stream>>>(rel, relb,
        Wq1_b, Wk_b, Wq2_b, Wv_b, Wg_b, bias3, bias2);
    wtrans6<<<dim3(16, 16, 6), blk, 0, stream>>>(
        Wq1_w, Wk_w, Wq2_w, Wv_w, Wg_w, Wo_w,
        qkvT, qkvT + 1024*1024, qkvT + 2048*1024,
        wvwgT, wvwgT + 1024*1024, WoT);
    wtrans_ff<<<dim3(64, 16, 2), blk, 0, stream>>>(ff1_w, ff2_w, ff1T, ff2T);

    // merged q1|k|q2 projection: 64x128 tiles, grid 24x32 = 768 blocks (even)
    gemm_mfma<2, 2, 0, 0, 1><<<dim3(24, 32, 1), blk, 0, stream>>>(
        jbf, qkvT, bias3, nullptr, qkv, QKVLD, D_, D_, D_, QKVLD, 0, 0, 0, 0, 0);
    // arf[bh,i,r] = q2 . rel  (A = qkv q2 third, stride 3072)
    gemm_mfma<4, 2, 0, 0, 1><<<dim3(2, 8, 32), blk, 0, stream>>>(
        qkv + 2 * D_, relb, nullptr, nullptr, arfb,
        R_, DH_, QKVLD, D_, R_,
        (size_t)I_ * QKVLD, (size_t)DH_, 0, (size_t)DH_, (size_t)I_ * R_);

    // value/gate: merged Wv|Wg GEMM, split epilogue (f32 vbuf | bf16 gbuf)
    ln_kernel<1><<<MROWS, blk, 0, stream>>>(x, xnb, ln1_g, ln1_b);
    gemm_mfma<2, 2, 1, 0, 2><<<dim3(16, 32, 1), blk, 0, stream>>>(
        xnb, wvwgT, bias2, (const float*)gbuf, vbuf, 2 * D_, D_, D_, D_, D_, 0, 0, 0, 0, 0);
    ln_kernel<0><<<MROWS, blk, 0, stream>>>(vbuf, vbuf, lnv_g, lnv_b);
    vtrans<<<dim3(16, 32), blk, 0, stream>>>(vbuf, vt);   // xnb dead -> vt slot

    // fused attention: two-pass flash, KVBLK=128 pair processing
    flash_attn6<<<dim3(16, 32), blk, 0, stream>>>(qkv, vt, arfb, gbuf, a_out, obuf);

    // output projection + residual, FF block
    gemm_mfma<2, 1, 0, 1, 0><<<dim3(16, 16, 1), blk, 0, stream>>>(
        obuf, WoT, Wo_b, x, x1, D_, D_, D_, D_, D_, 0, 0, 0, 0, 0);
    ln_kernel<1><<<MROWS, blk, 0, stream>>>(x1, x1nb, ln2_g, ln2_b);
    gemm_mfma<4, 2, 2, 0, 1><<<dim3(32, 16, 1), blk, 0, stream>>>(
        x1nb, ff1T, ff1_b, nullptr, hbuf, FF_, D_, D_, D_, FF_, 0, 0, 0, 0, 0);
    gemm_mfma<2, 1, 0, 1, 0><<<dim3(16, 16, 1), blk, 0, stream>>>(
        hbuf, ff2T, ff2_b, x1, out0, D_, FF_, FF_, FF_, D_, 0, 0, 0, 0, 0);
}

// Round 15
// 265.311 us; speedup vs baseline: 1.0247x; 1.0247x over previous
//
#include <hip/hip_runtime.h>
#include <hip/hip_bf16.h>
#include <math.h>

// PosNetEncoder: B=2, I=J=1024, D=1024, H=16, DH=64, K=64 (R=129), FF=4096
#define D_   1024
#define H_   16
#define DH_  64
#define FF_  4096
#define R_   129
#define I_   1024
#define B_   2
#define MROWS 2048   // B_*I_
#define QKVLD 3072   // merged q1|k|q2 row stride

typedef __bf16 v8bf16 __attribute__((ext_vector_type(8)));
typedef float f32x4 __attribute__((ext_vector_type(4)));

__device__ __forceinline__ float gelu_f(float x) {
    return 0.5f * x * (1.0f + erff(x * 0.7071067811865476f));
}

__device__ __forceinline__ void ldsld16(const void* g, void* l) {
    __builtin_amdgcn_global_load_lds(
        (const __attribute__((address_space(1))) void*)g,
        (__attribute__((address_space(3))) void*)l, 16, 0, 0);
}

// ---------------- fp32 -> bf16 convert (vector-4) ---------------------------
__global__ __launch_bounds__(256) void cvt_bf16(const float* __restrict__ in,
        __hip_bfloat16* __restrict__ out, int n4) {
    int i = blockIdx.x * 256 + threadIdx.x;
    if (i >= n4) return;
    float4 v = reinterpret_cast<const float4*>(in)[i];
    union { __hip_bfloat16 h[4]; uint2 u; } pk;
    pk.h[0] = __float2bfloat16(v.x); pk.h[1] = __float2bfloat16(v.y);
    pk.h[2] = __float2bfloat16(v.z); pk.h[3] = __float2bfloat16(v.w);
    reinterpret_cast<uint2*>(out)[i] = pk.u;
}

// ---- rel cvt (blocks 0..128) + bias concat copies (blocks 129..133) --------
__global__ __launch_bounds__(256) void cvt_rel_bias(const float* __restrict__ rel,
        __hip_bfloat16* __restrict__ relb,
        const float* __restrict__ q1b_, const float* __restrict__ kb_,
        const float* __restrict__ q2b_, const float* __restrict__ vb_,
        const float* __restrict__ gb_,
        float* __restrict__ bias3, float* __restrict__ bias2) {
    int bid = blockIdx.x, t = threadIdx.x;
    if (bid < 129) {
        int i = bid * 256 + t;
        float4 v = reinterpret_cast<const float4*>(rel)[i];
        union { __hip_bfloat16 h[4]; uint2 u; } pk;
        pk.h[0] = __float2bfloat16(v.x); pk.h[1] = __float2bfloat16(v.y);
        pk.h[2] = __float2bfloat16(v.z); pk.h[3] = __float2bfloat16(v.w);
        reinterpret_cast<uint2*>(relb)[i] = pk.u;
    } else {
        int k = bid - 129;   // 0..4 -> q1,k,q2 (bias3) ; v,g (bias2)
        const float* src = k == 0 ? q1b_ : k == 1 ? kb_ : k == 2 ? q2b_ : k == 3 ? vb_ : gb_;
        float* dst = (k < 3 ? bias3 + k * D_ : bias2 + (k - 3) * D_);
        reinterpret_cast<float4*>(dst)[t] = reinterpret_cast<const float4*>(src)[t];
    }
}

// ------ 6x batched D_xD_ transpose (one dispatch, z selects weight) ---------
__global__ __launch_bounds__(256) void wtrans6(
        const float* __restrict__ s0, const float* __restrict__ s1,
        const float* __restrict__ s2, const float* __restrict__ s3,
        const float* __restrict__ s4, const float* __restrict__ s5,
        __hip_bfloat16* __restrict__ d0, __hip_bfloat16* __restrict__ d1,
        __hip_bfloat16* __restrict__ d2, __hip_bfloat16* __restrict__ d3,
        __hip_bfloat16* __restrict__ d4, __hip_bfloat16* __restrict__ d5) {
    __shared__ float T[64][65];
    int z = blockIdx.z;
    const float* W = z == 0 ? s0 : z == 1 ? s1 : z == 2 ? s2 : z == 3 ? s3 : z == 4 ? s4 : s5;
    __hip_bfloat16* WT = z == 0 ? d0 : z == 1 ? d1 : z == 2 ? d2 : z == 3 ? d3 : z == 4 ? d4 : d5;
    int k0 = blockIdx.y * 64, n0 = blockIdx.x * 64;
    int t = threadIdx.x;
#pragma unroll
    for (int i = 0; i < 16; i++) {
        int e = t + i * 256, r = e >> 6, c = e & 63;
        T[r][c] = W[(size_t)(k0 + r) * D_ + n0 + c];
    }
    __syncthreads();
#pragma unroll
    for (int i = 0; i < 16; i++) {
        int e = t + i * 256, r = e >> 6, c = e & 63;
        WT[(size_t)(n0 + r) * D_ + k0 + c] = __float2bfloat16(T[c][r]);
    }
}

// ------ ff1 + ff2 transposes in one dispatch (z=0: ff1, z=1: ff2) -----------
__global__ __launch_bounds__(256) void wtrans_ff(
        const float* __restrict__ f1, const float* __restrict__ f2,
        __hip_bfloat16* __restrict__ d1, __hip_bfloat16* __restrict__ d2) {
    __shared__ float T[64][65];
    int z = blockIdx.z;
    const float* W = z == 0 ? f1 : f2;
    __hip_bfloat16* WT = z == 0 ? d1 : d2;
    int K = z == 0 ? D_ : FF_;
    int N = z == 0 ? FF_ : D_;
    int k0 = (z == 0 ? blockIdx.y : blockIdx.x) * 64;
    int n0 = (z == 0 ? blockIdx.x : blockIdx.y) * 64;
    int t = threadIdx.x;
#pragma unroll
    for (int i = 0; i < 16; i++) {
        int e = t + i * 256, r = e >> 6, c = e & 63;
        T[r][c] = W[(size_t)(k0 + r) * N + n0 + c];
    }
    __syncthreads();
#pragma unroll
    for (int i = 0; i < 16; i++) {
        int e = t + i * 256, r = e >> 6, c = e & 63;
        WT[(size_t)(n0 + r) * K + k0 + c] = __float2bfloat16(T[c][r]);
    }
}

// ---- v[b,j,h,d] fp32 -> vt[b,h,d,j] bf16 (64x64 tiles) ---------------------
__global__ __launch_bounds__(256) void vtrans(const float* __restrict__ v,
        __hip_bfloat16* __restrict__ vt) {
    __shared__ float T[64][65];
    int z = blockIdx.y, b = z >> 4, h = z & 15;
    int j0 = blockIdx.x * 64;
    int t = threadIdx.x;
#pragma unroll
    for (int i = 0; i < 16; i++) {
        int e = t + i * 256, r = e >> 6, c = e & 63;   // r=j, c=d
        T[r][c] = v[(size_t)(b * I_ + j0 + r) * D_ + h * DH_ + c];
    }
    __syncthreads();
#pragma unroll
    for (int i = 0; i < 16; i++) {
        int e = t + i * 256, r = e >> 6, c = e & 63;   // r=d, c=j
        vt[((size_t)z * DH_ + r) * I_ + j0 + c] = __float2bfloat16(T[c][r]);
    }
}

// ---------------- MFMA bf16 GEMM: C = epi(A[M,K] @ Bt[N,K]^T) ---------------
// Tile BM = (4/NWC)*MR*16 x BN = NWC*64, 4 waves, 16x16x32 MFMA.
// OUTBF: 0 f32 out, 1 bf16 out, 2 split (col<D_ -> f32 Cout, else bf16 via res).
template<int MR, int NWC, int ACT, int RES, int OUTBF>
__global__ __launch_bounds__(256) void gemm_mfma(
        const __hip_bfloat16* __restrict__ A,
        const __hip_bfloat16* __restrict__ Bt,
        const float* __restrict__ bias,
        const float* __restrict__ res,
        void* __restrict__ Cout,
        int N, int Kd, int lda, int ldb, int ldc,
        size_t sAb, size_t sAh, size_t sBb, size_t sBh, size_t sCz) {
    constexpr int NWR = 4 / NWC;
    constexpr int BM = NWR * MR * 16;
    constexpr int BN = NWC * 64;
    __shared__ __align__(16) __hip_bfloat16 As[BM * 64];
    __shared__ __align__(16) __hip_bfloat16 Bs[BN * 64];
    const char* AsB = (const char*)As;
    const char* BsB = (const char*)Bs;
    int z = blockIdx.z;
    const __hip_bfloat16* Ab = A + (size_t)(z >> 4) * sAb + (size_t)(z & 15) * sAh;
    const __hip_bfloat16* Bb = Bt + (size_t)(z >> 4) * sBb + (size_t)(z & 15) * sBh;
    float* Cf = (float*)Cout + (size_t)z * sCz;
    __hip_bfloat16* Cb = (__hip_bfloat16*)Cout + (size_t)z * sCz;
    int m0 = blockIdx.y * BM, n0 = blockIdx.x * BN;
    int t = threadIdx.x;
    int l = t & 63, w = t >> 6;
    int wr = w / NWC, wc = w % NWC;
    int lr = l & 15, kq = l >> 4;
    int rx = lr & 7;

    f32x4 acc[MR][4] = {};

    for (int k0 = 0; k0 < Kd; k0 += 64) {
#pragma unroll
        for (int i = 0; i < BM / 32; i++) {
            int e = t + i * 256;
            int row = e >> 3, sl = e & 7;
            int kb = sl ^ (row & 7);
            ldsld16(Ab + (size_t)(m0 + row) * lda + (k0 + kb * 8), (void*)(AsB + e * 16));
        }
#pragma unroll
        for (int i = 0; i < BN / 32; i++) {
            int e = t + i * 256;
            int row = e >> 3, sl = e & 7;
            int kb = sl ^ (row & 7);
            int nr = n0 + row; if (nr > N - 1) nr = N - 1;   // tail tile (arf N=129)
            ldsld16(Bb + (size_t)nr * ldb + (k0 + kb * 8), (void*)(BsB + e * 16));
        }
        __syncthreads();
#pragma unroll
        for (int kc = 0; kc < 2; kc++) {
            int sloff = (((kc << 2) + kq) ^ rx) << 4;
            v8bf16 af[MR], bfr[4];
#pragma unroll
            for (int mr = 0; mr < MR; mr++)
                af[mr] = *(const v8bf16*)(AsB + ((wr * (MR * 16) + mr * 16 + lr) << 7) + sloff);
#pragma unroll
            for (int nc = 0; nc < 4; nc++)
                bfr[nc] = *(const v8bf16*)(BsB + ((wc * 64 + nc * 16 + lr) << 7) + sloff);
#pragma unroll
            for (int mr = 0; mr < MR; mr++)
#pragma unroll
                for (int nc = 0; nc < 4; nc++)
                    acc[mr][nc] = __builtin_amdgcn_mfma_f32_16x16x32_bf16(
                        af[mr], bfr[nc], acc[mr][nc], 0, 0, 0);
        }
        __syncthreads();
    }

#pragma unroll
    for (int mr = 0; mr < MR; mr++) {
        int rbase = m0 + wr * (MR * 16) + mr * 16 + kq * 4;
#pragma unroll
        for (int nc = 0; nc < 4; nc++) {
            int col = n0 + wc * 64 + nc * 16 + lr;
            bool okc = col < N;
            float bv = (bias && okc) ? bias[col] : 0.f;
#pragma unroll
            for (int ri = 0; ri < 4; ri++) {
                int r = rbase + ri;
                float val = acc[mr][nc][ri] + bv;
                if (ACT == 1) val = gelu_f(val);
                if (ACT == 2) val = fmaxf(val, 0.f);
                if (RES) val += res[(size_t)r * ldc + col];
                if (okc) {
                    if (OUTBF == 2) {
                        if (col < D_) Cf[(size_t)r * ldc + col] = val;
                        else ((__hip_bfloat16*)res)[(size_t)r * ldc + (col - D_)] =
                                 __float2bfloat16(val);
                    } else if (OUTBF == 1) {
                        Cb[(size_t)r * ldc + col] = __float2bfloat16(val);
                    } else {
                        Cf[(size_t)r * ldc + col] = val;
                    }
                }
            }
        }
    }
}

// ---------------- fused attention, two-pass flash (exp2 space) --------------
// Block = 64 q-rows x one (b,h); wave w owns rows w*16..w*16+15.
// R12 structure + COALESCED a_out write: p-phase writes only LDS pB; after
// the PV MFMA a cooperative phase streams pB -> a_out in 256B segments
// (lane l -> row l>>4, col (l&15)*4, nontemporal f32x4 ext-vector stores).
#define FA_AR 0                       // 64*132*2 = 16896 B
#define FA_K  16896                   // 64x64 bf16 = 8192 B
#define FA_V  (16896 + 8192)          // 8192 B
#define FA_P  (16896 + 16384)         // 8192 B (p tile; also initial Q staging)
#define SC2   0.1803368801111244f     // 0.125 * log2(e)
__global__ __launch_bounds__(256) void flash_attn7(
        const __hip_bfloat16* __restrict__ qkv,
        const __hip_bfloat16* __restrict__ vt,
        const __hip_bfloat16* __restrict__ arfb,
        const __hip_bfloat16* __restrict__ gb,
        float* __restrict__ a_out,
        __hip_bfloat16* __restrict__ obuf) {
    __shared__ __align__(16) char lds[16896 + 8192 * 3];
    __hip_bfloat16* arl = (__hip_bfloat16*)(lds + FA_AR);
    char* kB = lds + FA_K;
    char* vB = lds + FA_V;
    char* pB = lds + FA_P;

    int z = blockIdx.y, b = z >> 4, h = z & 15;
    int i0 = blockIdx.x * 64;
    int t = threadIdx.x, l = t & 63, w = t >> 6;
    int lr = l & 15, kq = l >> 4;

    // stage Q (64 rows x 64 d, swizzled) into pB; arf rows into arl
#pragma unroll
    for (int i = 0; i < 2; i++) {
        int e = t + i * 256;
        int row = e >> 3, sl = e & 7;
        int kb = sl ^ (row & 7);
        ldsld16(qkv + (size_t)(b * I_ + i0 + row) * QKVLD + h * DH_ + kb * 8,
                (void*)(pB + e * 16));
    }
    for (int idx = t; idx < 64 * 132; idx += 256) {
        int row = idx / 132, r = idx - row * 132;
        if (r < R_) arl[idx] = arfb[((size_t)z * I_ + i0 + row) * R_ + r];
    }
    __syncthreads();
    v8bf16 qf[2];
#pragma unroll
    for (int kc = 0; kc < 2; kc++)
        qf[kc] = *(const v8bf16*)(pB + ((w * 16 + lr) << 7) + ((((kc << 2) + kq) ^ (lr & 7)) << 4));

    int irow = w * 16 + kq * 4;      // lane's first row within 64
    int ig = i0 + irow;              // global i for ri=0
    float loS[4], hiS[4];
#pragma unroll
    for (int ri = 0; ri < 4; ri++) {
        loS[ri] = __bfloat162float(arl[(irow + ri) * 132 + 0])   * SC2;
        hiS[ri] = __bfloat162float(arl[(irow + ri) * 132 + 128]) * SC2;
    }

    // ---- pass A: per-lane l = sum exp2(s2) --------------------------------
    float l_ln[4] = {0.f, 0.f, 0.f, 0.f};
    for (int jt = 0; jt < 16; jt++) {
        int j0 = jt * 64;
#pragma unroll
        for (int i = 0; i < 2; i++) {
            int e = t + i * 256;
            int row = e >> 3, sl = e & 7;
            int kb = sl ^ (row & 7);
            ldsld16(qkv + (size_t)(b * I_ + j0 + row) * QKVLD + D_ + h * DH_ + kb * 8,
                    (void*)(kB + e * 16));
        }
        __syncthreads();
        f32x4 acc[4] = {};
        __builtin_amdgcn_s_setprio(1);
#pragma unroll
        for (int kc = 0; kc < 2; kc++) {
            int sloff = ((((kc << 2) + kq)) ^ (lr & 7)) << 4;
#pragma unroll
            for (int tt = 0; tt < 4; tt++) {
                v8bf16 kf = *(const v8bf16*)(kB + ((tt * 16 + lr) << 7) + sloff);
                acc[tt] = __builtin_amdgcn_mfma_f32_16x16x32_bf16(qf[kc], kf, acc[tt], 0, 0, 0);
            }
        }
        __builtin_amdgcn_s_setprio(0);
#pragma unroll
        for (int ri = 0; ri < 4; ri++) {
            int i_g = ig + ri;
            float sc[4];
            bool lo_all = (j0 + 63) <= (i_g - 64);
            bool hi_all = j0 >= (i_g + 64);
            if (lo_all || hi_all) {
                float c = lo_all ? loS[ri] : hiS[ri];
#pragma unroll
                for (int tt = 0; tt < 4; tt++) sc[tt] = fmaf(acc[tt][ri], SC2, c);
            } else {
#pragma unroll
                for (int tt = 0; tt < 4; tt++) {
                    int rel = j0 + tt * 16 + lr - i_g;
                    rel = rel < -64 ? -64 : (rel > 64 ? 64 : rel);
                    sc[tt] = (acc[tt][ri] + __bfloat162float(arl[(irow + ri) * 132 + rel + 64])) * SC2;
                }
            }
            l_ln[ri] += exp2f(sc[0]) + exp2f(sc[1]) + exp2f(sc[2]) + exp2f(sc[3]);
        }
        __syncthreads();
    }
    float offb[4];
#pragma unroll
    for (int ri = 0; ri < 4; ri++) {
        float s = l_ln[ri];
#pragma unroll
        for (int off = 1; off < 16; off <<= 1) s += __shfl_xor(s, off, 64);
        offb[ri] = __log2f(s);
    }

    // ---- pass B: p -> pB; PV; coalesced a_out write from pB ---------------
    f32x4 oacc[4] = {};
    for (int jt = 0; jt < 16; jt++) {
        int j0 = jt * 64;
#pragma unroll
        for (int i = 0; i < 2; i++) {
            int e = t + i * 256;
            int row = e >> 3, sl = e & 7;
            int kb = sl ^ (row & 7);
            ldsld16(qkv + (size_t)(b * I_ + j0 + row) * QKVLD + D_ + h * DH_ + kb * 8,
                    (void*)(kB + e * 16));
            ldsld16(vt + ((size_t)z * DH_ + row) * I_ + j0 + kb * 8,
                    (void*)(vB + e * 16));
        }
        __syncthreads();
        f32x4 acc[4] = {};
        __builtin_amdgcn_s_setprio(1);
#pragma unroll
        for (int kc = 0; kc < 2; kc++) {
            int sloff = ((((kc << 2) + kq)) ^ (lr & 7)) << 4;
#pragma unroll
            for (int tt = 0; tt < 4; tt++) {
                v8bf16 kf = *(const v8bf16*)(kB + ((tt * 16 + lr) << 7) + sloff);
                acc[tt] = __builtin_amdgcn_mfma_f32_16x16x32_bf16(qf[kc], kf, acc[tt], 0, 0, 0);
            }
        }
        __builtin_amdgcn_s_setprio(0);
#pragma unroll
        for (int ri = 0; ri < 4; ri++) {
            int i_g = ig + ri;
            int rowl = irow + ri;
            float sc[4];
            bool lo_all = (j0 + 63) <= (i_g - 64);
            bool hi_all = j0 >= (i_g + 64);
            if (lo_all || hi_all) {
                float c = lo_all ? loS[ri] : hiS[ri];
#pragma unroll
                for (int tt = 0; tt < 4; tt++) sc[tt] = fmaf(acc[tt][ri], SC2, c);
            } else {
#pragma unroll
                for (int tt = 0; tt < 4; tt++) {
                    int rel = j0 + tt * 16 + lr - i_g;
                    rel = rel < -64 ? -64 : (rel > 64 ? 64 : rel);
                    sc[tt] = (acc[tt][ri] + __bfloat162float(arl[rowl * 132 + rel + 64])) * SC2;
                }
            }
#pragma unroll
            for (int tt = 0; tt < 4; tt++) {
                float p = exp2f(sc[tt] - offb[ri]);
                *(__hip_bfloat16*)(pB + (rowl << 7) +
                        ((((tt * 2) + (lr >> 3)) ^ (rowl & 7)) << 4) + (lr & 7) * 2) =
                    __float2bfloat16(p);
            }
        }
        __syncthreads();
        __builtin_amdgcn_s_setprio(1);
#pragma unroll
        for (int kc = 0; kc < 2; kc++) {
            int sloff = ((((kc << 2) + kq)) ^ (lr & 7)) << 4;
            v8bf16 pf = *(const v8bf16*)(pB + ((w * 16 + lr) << 7) + sloff);
#pragma unroll
            for (int nc = 0; nc < 4; nc++) {
                v8bf16 vf = *(const v8bf16*)(vB + ((nc * 16 + lr) << 7) + sloff);
                oacc[nc] = __builtin_amdgcn_mfma_f32_16x16x32_bf16(pf, vf, oacc[nc], 0, 0, 0);
            }
        }
        __builtin_amdgcn_s_setprio(0);
        // coalesced a_out write from pB (256B segments per wave-instruction):
        // unit idx = t + g*256 -> row idx>>4, col (idx&15)*4; f32x4 stores.
        {
            float* gbase = a_out + ((size_t)z * I_ + i0) * I_ + j0;
#pragma unroll
            for (int g = 0; g < 4; g++) {
                int idx = t + g * 256;
                int row = idx >> 4, c4 = (idx & 15) * 4;
                const __hip_bfloat16* ph = (const __hip_bfloat16*)(pB + (row << 7) +
                        (((c4 >> 3) ^ (row & 7)) << 4) + (c4 & 7) * 2);
                f32x4 o4;
                o4[0] = __bfloat162float(ph[0]); o4[1] = __bfloat162float(ph[1]);
                o4[2] = __bfloat162float(ph[2]); o4[3] = __bfloat162float(ph[3]);
                __builtin_nontemporal_store(o4,
                        (f32x4*)(gbase + (size_t)row * I_ + c4));
            }
        }
        __syncthreads();
    }
#pragma unroll
    for (int nc = 0; nc < 4; nc++) {
#pragma unroll
        for (int ri = 0; ri < 4; ri++) {
            int r = i0 + irow + ri;
            size_t oi = ((size_t)(b * I_ + r)) * D_ + h * DH_ + nc * 16 + lr;
            obuf[oi] = __float2bfloat16(oacc[nc][ri] * __bfloat162float(gb[oi]));
        }
    }
}

// ---------------- LayerNorm rows of 1024 (256 thr, float4) ------------------
template<int OUTBF>
__global__ __launch_bounds__(256) void ln_kernel(const float* __restrict__ in,
        void* __restrict__ out, const float* __restrict__ gw,
        const float* __restrict__ bw) {
    __shared__ float shs[4], shq[4];
    int row = blockIdx.x;
    int t = threadIdx.x;
    float4 v = reinterpret_cast<const float4*>(in + (size_t)row * D_)[t];
    float s = v.x + v.y + v.z + v.w;
#pragma unroll
    for (int off = 32; off > 0; off >>= 1) s += __shfl_down(s, off, 64);
    if ((t & 63) == 0) shs[t >> 6] = s;
    __syncthreads();
    float mean = (shs[0] + shs[1] + shs[2] + shs[3]) * (1.0f / D_);
    float d0 = v.x - mean, d1 = v.y - mean, d2 = v.z - mean, d3 = v.w - mean;
    float q = d0 * d0 + d1 * d1 + d2 * d2 + d3 * d3;
#pragma unroll
    for (int off = 32; off > 0; off >>= 1) q += __shfl_down(q, off, 64);
    if ((t & 63) == 0) shq[t >> 6] = q;
    __syncthreads();
    float var = (shq[0] + shq[1] + shq[2] + shq[3]) * (1.0f / D_);
    float rstd = rsqrtf(var + 1e-5f);
    float4 g4 = reinterpret_cast<const float4*>(gw)[t];
    float4 b4 = reinterpret_cast<const float4*>(bw)[t];
    float o0 = d0 * rstd * g4.x + b4.x;
    float o1 = d1 * rstd * g4.y + b4.y;
    float o2 = d2 * rstd * g4.z + b4.z;
    float o3 = d3 * rstd * g4.w + b4.w;
    if (OUTBF) {
        union { __hip_bfloat16 h[4]; uint2 u; } pk;
        pk.h[0] = __float2bfloat16(o0); pk.h[1] = __float2bfloat16(o1);
        pk.h[2] = __float2bfloat16(o2); pk.h[3] = __float2bfloat16(o3);
        reinterpret_cast<uint2*>((__hip_bfloat16*)out + (size_t)row * D_)[t] = pk.u;
    } else {
        float4 o; o.x = o0; o.y = o1; o.z = o2; o.w = o3;
        reinterpret_cast<float4*>((float*)out + (size_t)row * D_)[t] = o;
    }
}

extern "C" void kernel_launch(void* const* d_in, const int* in_sizes, int n_in,
                              void* d_out, int out_size, void* d_ws, size_t ws_size,
                              hipStream_t stream) {
    const float* x      = (const float*)d_in[0];
    const float* jin    = (const float*)d_in[1];
    const float* ln1_g  = (const float*)d_in[2];
    const float* ln1_b  = (const float*)d_in[3];
    const float* Wv_w   = (const float*)d_in[4];
    const float* Wv_b   = (const float*)d_in[5];
    const float* Wg_w   = (const float*)d_in[6];
    const float* Wg_b   = (const float*)d_in[7];
    const float* lnv_g  = (const float*)d_in[8];
    const float* lnv_b  = (const float*)d_in[9];
    const float* Wq1_w  = (const float*)d_in[10];
    const float* Wq1_b  = (const float*)d_in[11];
    const float* Wk_w   = (const float*)d_in[12];
    const float* Wk_b   = (const float*)d_in[13];
    const float* Wq2_w  = (const float*)d_in[14];
    const float* Wq2_b  = (const float*)d_in[15];
    const float* rel    = (const float*)d_in[16];
    const float* Wo_w   = (const float*)d_in[17];
    const float* Wo_b   = (const float*)d_in[18];
    const float* ln2_g  = (const float*)d_in[19];
    const float* ln2_b  = (const float*)d_in[20];
    const float* ff1_w  = (const float*)d_in[21];
    const float* ff1_b  = (const float*)d_in[22];
    const float* ff2_w  = (const float*)d_in[23];
    const float* ff2_b  = (const float*)d_in[24];
    // d_in[25] = indices: computed analytically on device

    float* out0  = (float*)d_out;
    float* a_out = out0 + (size_t)B_ * I_ * D_;    // [B,H,I,J]

    char* wsb = (char*)d_ws;
    const size_t MB = 1u << 20;
    // persistent bf16 transposed weights [0,28MB)
    __hip_bfloat16* wvwgT= (__hip_bfloat16*)(wsb + 0 * MB);   // [2048,1024] 4MB
    __hip_bfloat16* qkvT = (__hip_bfloat16*)(wsb + 4 * MB);   // [3072,1024] 6MB
    __hip_bfloat16* WoT  = (__hip_bfloat16*)(wsb + 10 * MB);
    __hip_bfloat16* ff1T = (__hip_bfloat16*)(wsb + 12 * MB);  // [4096,1024] 8MB
    __hip_bfloat16* ff2T = (__hip_bfloat16*)(wsb + 20 * MB);  // [1024,4096] 8MB
    // activations, slot-reused along the timeline
    __hip_bfloat16* jbf  = (__hip_bfloat16*)(wsb + 28 * MB);  // dead after qkv GEMM
    __hip_bfloat16* qkv  = (__hip_bfloat16*)(wsb + 32 * MB);  // [2048,3072] 12MB, live->flash
    __hip_bfloat16* relb = (__hip_bfloat16*)(wsb + 44 * MB);  // 0.26MB, dead after arf
    __hip_bfloat16* arfb = (__hip_bfloat16*)(wsb + 45 * MB);  // 8.06MB, live->flash
    __hip_bfloat16* gbuf = (__hip_bfloat16*)(wsb + 54 * MB);  // 4MB, live->flash
    float*          vbuf = (float*)        (wsb + 58 * MB);   // 8MB f32, dead after vtrans
    __hip_bfloat16* xnb  = (__hip_bfloat16*)(wsb + 28 * MB);  // reuse jbf (dead after WvWg)
    __hip_bfloat16* vt   = (__hip_bfloat16*)(wsb + 28 * MB);  // reuse xnb, live->flash
    __hip_bfloat16* obuf = (__hip_bfloat16*)(wsb + 58 * MB);  // reuse vbuf (dead)
    float*          x1   = (float*)        (wsb + 32 * MB);   // reuse qkv (dead after flash)
    __hip_bfloat16* x1nb = (__hip_bfloat16*)(wsb + 40 * MB);  // reuse qkv tail (dead)
    __hip_bfloat16* hbuf = (__hip_bfloat16*)(wsb + 44 * MB);  // 16MB, 44-60 (all dead)
    float*          bias3= (float*)        (wsb + 66 * MB);   // [3072] f32 concat
    float*          bias2= (float*)        (wsb + 66 * MB + 16384);  // [2048] f32 concat

    dim3 blk(256);

    // prologue: 4 dispatches
    cvt_bf16<<<2048, blk, 0, stream>>>(jin, jbf, (MROWS * D_) / 4);
    cvt_rel_bias<<<134, blk, 0, stream>>>(rel, relb,
        Wq1_b, Wk_b, Wq2_b, Wv_b, Wg_b, bias3, bias2);
    wtrans6<<<dim3(16, 16, 6), blk, 0, stream>>>(
        Wq1_w, Wk_w, Wq2_w, Wv_w, Wg_w, Wo_w,
        qkvT, qkvT + 1024*1024, qkvT + 2048*1024,
        wvwgT, wvwgT + 1024*1024, WoT);
    wtrans_ff<<<dim3(64, 16, 2), blk, 0, stream>>>(ff1_w, ff2_w, ff1T, ff2T);

    // merged q1|k|q2 projection: 64x128 tiles, grid 24x32 = 768 blocks (even)
    gemm_mfma<2, 2, 0, 0, 1><<<dim3(24, 32, 1), blk, 0, stream>>>(
        jbf, qkvT, bias3, nullptr, qkv, QKVLD, D_, D_, D_, QKVLD, 0, 0, 0, 0, 0);
    // arf[bh,i,r] = q2 . rel  (A = qkv q2 third, stride 3072)
    gemm_mfma<4, 2, 0, 0, 1><<<dim3(2, 8, 32), blk, 0, stream>>>(
        qkv + 2 * D_, relb, nullptr, nullptr, arfb,
        R_, DH_, QKVLD, D_, R_,
        (size_t)I_ * QKVLD, (size_t)DH_, 0, (size_t)DH_, (size_t)I_ * R_);

    // value/gate: merged Wv|Wg GEMM, split epilogue (f32 vbuf | bf16 gbuf)
    ln_kernel<1><<<MROWS, blk, 0, stream>>>(x, xnb, ln1_g, ln1_b);
    gemm_mfma<2, 2, 1, 0, 2><<<dim3(16, 32, 1), blk, 0, stream>>>(
        xnb, wvwgT, bias2, (const float*)gbuf, vbuf, 2 * D_, D_, D_, D_, D_, 0, 0, 0, 0, 0);
    ln_kernel<0><<<MROWS, blk, 0, stream>>>(vbuf, vbuf, lnv_g, lnv_b);
    vtrans<<<dim3(16, 32), blk, 0, stream>>>(vbuf, vt);   // xnb dead -> vt slot

    // fused attention: two-pass flash, coalesced a_out write
    flash_attn7<<<dim3(16, 32), blk, 0, stream>>>(qkv, vt, arfb, gbuf, a_out, obuf);

    // output projection + residual, FF block
    gemm_mfma<2, 1, 0, 1, 0><<<dim3(16, 16, 1), blk, 0, stream>>>(
        obuf, WoT, Wo_b, x, x1, D_, D_, D_, D_, D_, 0, 0, 0, 0, 0);
    ln_kernel<1><<<MROWS, blk, 0, stream>>>(x1, x1nb, ln2_g, ln2_b);
    gemm_mfma<4, 2, 2, 0, 1><<<dim3(32, 16, 1), blk, 0, stream>>>(
        x1nb, ff1T, ff1_b, nullptr, hbuf, FF_, D_, D_, D_, FF_, 0, 0, 0, 0, 0);
    gemm_mfma<2, 1, 0, 1, 0><<<dim3(16, 16, 1), blk, 0, stream>>>(
        hbuf, ff2T, ff2_b, x1, out0, D_, FF_, FF_, FF_, D_, 0, 0, 0, 0, 0);
}

// Round 17
// 263.047 us; speedup vs baseline: 1.0335x; 1.0086x over previous
//
#include <hip/hip_runtime.h>
#include <hip/hip_bf16.h>
#include <math.h>

// PosNetEncoder: B=2, I=J=1024, D=1024, H=16, DH=64, K=64 (R=129), FF=4096
#define D_   1024
#define H_   16
#define DH_  64
#define FF_  4096
#define R_   129
#define I_   1024
#define B_   2
#define MROWS 2048   // B_*I_
#define QKVLD 3072   // merged q1|k|q2 row stride

typedef __bf16 v8bf16 __attribute__((ext_vector_type(8)));
typedef float f32x4 __attribute__((ext_vector_type(4)));

__device__ __forceinline__ float gelu_f(float x) {
    return 0.5f * x * (1.0f + erff(x * 0.7071067811865476f));
}

__device__ __forceinline__ void ldsld16(const void* g, void* l) {
    __builtin_amdgcn_global_load_lds(
        (const __attribute__((address_space(1))) void*)g,
        (__attribute__((address_space(3))) void*)l, 16, 0, 0);
}

// ---------------- fp32 -> bf16 convert (vector-4) ---------------------------
__global__ __launch_bounds__(256) void cvt_bf16(const float* __restrict__ in,
        __hip_bfloat16* __restrict__ out, int n4) {
    int i = blockIdx.x * 256 + threadIdx.x;
    if (i >= n4) return;
    float4 v = reinterpret_cast<const float4*>(in)[i];
    union { __hip_bfloat16 h[4]; uint2 u; } pk;
    pk.h[0] = __float2bfloat16(v.x); pk.h[1] = __float2bfloat16(v.y);
    pk.h[2] = __float2bfloat16(v.z); pk.h[3] = __float2bfloat16(v.w);
    reinterpret_cast<uint2*>(out)[i] = pk.u;
}

// ---- rel cvt (blocks 0..128) + bias concat copies (blocks 129..133) --------
__global__ __launch_bounds__(256) void cvt_rel_bias(const float* __restrict__ rel,
        __hip_bfloat16* __restrict__ relb,
        const float* __restrict__ q1b_, const float* __restrict__ kb_,
        const float* __restrict__ q2b_, const float* __restrict__ vb_,
        const float* __restrict__ gb_,
        float* __restrict__ bias3, float* __restrict__ bias2) {
    int bid = blockIdx.x, t = threadIdx.x;
    if (bid < 129) {
        int i = bid * 256 + t;
        float4 v = reinterpret_cast<const float4*>(rel)[i];
        union { __hip_bfloat16 h[4]; uint2 u; } pk;
        pk.h[0] = __float2bfloat16(v.x); pk.h[1] = __float2bfloat16(v.y);
        pk.h[2] = __float2bfloat16(v.z); pk.h[3] = __float2bfloat16(v.w);
        reinterpret_cast<uint2*>(relb)[i] = pk.u;
    } else {
        int k = bid - 129;   // 0..4 -> q1,k,q2 (bias3) ; v,g (bias2)
        const float* src = k == 0 ? q1b_ : k == 1 ? kb_ : k == 2 ? q2b_ : k == 3 ? vb_ : gb_;
        float* dst = (k < 3 ? bias3 + k * D_ : bias2 + (k - 3) * D_);
        reinterpret_cast<float4*>(dst)[t] = reinterpret_cast<const float4*>(src)[t];
    }
}

// ------ 6x batched D_xD_ transpose (one dispatch, z selects weight) ---------
__global__ __launch_bounds__(256) void wtrans6(
        const float* __restrict__ s0, const float* __restrict__ s1,
        const float* __restrict__ s2, const float* __restrict__ s3,
        const float* __restrict__ s4, const float* __restrict__ s5,
        __hip_bfloat16* __restrict__ d0, __hip_bfloat16* __restrict__ d1,
        __hip_bfloat16* __restrict__ d2, __hip_bfloat16* __restrict__ d3,
        __hip_bfloat16* __restrict__ d4, __hip_bfloat16* __restrict__ d5) {
    __shared__ float T[64][65];
    int z = blockIdx.z;
    const float* W = z == 0 ? s0 : z == 1 ? s1 : z == 2 ? s2 : z == 3 ? s3 : z == 4 ? s4 : s5;
    __hip_bfloat16* WT = z == 0 ? d0 : z == 1 ? d1 : z == 2 ? d2 : z == 3 ? d3 : z == 4 ? d4 : d5;
    int k0 = blockIdx.y * 64, n0 = blockIdx.x * 64;
    int t = threadIdx.x;
#pragma unroll
    for (int i = 0; i < 16; i++) {
        int e = t + i * 256, r = e >> 6, c = e & 63;
        T[r][c] = W[(size_t)(k0 + r) * D_ + n0 + c];
    }
    __syncthreads();
#pragma unroll
    for (int i = 0; i < 16; i++) {
        int e = t + i * 256, r = e >> 6, c = e & 63;
        WT[(size_t)(n0 + r) * D_ + k0 + c] = __float2bfloat16(T[c][r]);
    }
}

// ------ ff1 + ff2 transposes in one dispatch (z=0: ff1, z=1: ff2) -----------
__global__ __launch_bounds__(256) void wtrans_ff(
        const float* __restrict__ f1, const float* __restrict__ f2,
        __hip_bfloat16* __restrict__ d1, __hip_bfloat16* __restrict__ d2) {
    __shared__ float T[64][65];
    int z = blockIdx.z;
    const float* W = z == 0 ? f1 : f2;
    __hip_bfloat16* WT = z == 0 ? d1 : d2;
    int K = z == 0 ? D_ : FF_;
    int N = z == 0 ? FF_ : D_;
    int k0 = (z == 0 ? blockIdx.y : blockIdx.x) * 64;
    int n0 = (z == 0 ? blockIdx.x : blockIdx.y) * 64;
    int t = threadIdx.x;
#pragma unroll
    for (int i = 0; i < 16; i++) {
        int e = t + i * 256, r = e >> 6, c = e & 63;
        T[r][c] = W[(size_t)(k0 + r) * N + n0 + c];
    }
    __syncthreads();
#pragma unroll
    for (int i = 0; i < 16; i++) {
        int e = t + i * 256, r = e >> 6, c = e & 63;
        WT[(size_t)(n0 + r) * K + k0 + c] = __float2bfloat16(T[c][r]);
    }
}

// ---- per-row mean/rstd for lnv (one block per row) -------------------------
__global__ __launch_bounds__(256) void rowstats(const float* __restrict__ in,
        float* __restrict__ stats) {
    __shared__ float shs[4], shq[4];
    int row = blockIdx.x;
    int t = threadIdx.x;
    float4 v = reinterpret_cast<const float4*>(in + (size_t)row * D_)[t];
    float s = v.x + v.y + v.z + v.w;
#pragma unroll
    for (int off = 32; off > 0; off >>= 1) s += __shfl_down(s, off, 64);
    if ((t & 63) == 0) shs[t >> 6] = s;
    __syncthreads();
    float mean = (shs[0] + shs[1] + shs[2] + shs[3]) * (1.0f / D_);
    float d0 = v.x - mean, d1 = v.y - mean, d2 = v.z - mean, d3 = v.w - mean;
    float q = d0 * d0 + d1 * d1 + d2 * d2 + d3 * d3;
#pragma unroll
    for (int off = 32; off > 0; off >>= 1) q += __shfl_down(q, off, 64);
    if ((t & 63) == 0) shq[t >> 6] = q;
    __syncthreads();
    if (t == 0) {
        float var = (shq[0] + shq[1] + shq[2] + shq[3]) * (1.0f / D_);
        stats[row * 2]     = mean;
        stats[row * 2 + 1] = rsqrtf(var + 1e-5f);
    }
}

// ---- v fp32 -> LN -> vt[b,h,d,j] bf16 (64x64 tiles), lnv fused -------------
__global__ __launch_bounds__(256) void vtrans_ln(const float* __restrict__ v,
        const float* __restrict__ stats, const float* __restrict__ gw,
        const float* __restrict__ bw, __hip_bfloat16* __restrict__ vt) {
    __shared__ float T[64][65];
    int z = blockIdx.y, b = z >> 4, h = z & 15;
    int j0 = blockIdx.x * 64;
    int t = threadIdx.x;
#pragma unroll
    for (int i = 0; i < 16; i++) {
        int e = t + i * 256, r = e >> 6, c = e & 63;   // r=j, c=d
        int grow = b * I_ + j0 + r;
        float mean = stats[grow * 2], rstd = stats[grow * 2 + 1];
        float g = gw[h * DH_ + c], bb = bw[h * DH_ + c];
        T[r][c] = (v[(size_t)grow * D_ + h * DH_ + c] - mean) * rstd * g + bb;
    }
    __syncthreads();
#pragma unroll
    for (int i = 0; i < 16; i++) {
        int e = t + i * 256, r = e >> 6, c = e & 63;   // r=d, c=j
        vt[((size_t)z * DH_ + r) * I_ + j0 + c] = __float2bfloat16(T[c][r]);
    }
}

// ---------------- MFMA bf16 GEMM: C = epi(A[M,K] @ Bt[N,K]^T) ---------------
// RES: 0 none, 1 f32 residual, 2 bf16 residual.
// OUTBF: 0 f32 out, 1 bf16 out, 2 split (col<D_ -> f32 Cout, else bf16 via res).
template<int MR, int NWC, int ACT, int RES, int OUTBF>
__global__ __launch_bounds__(256) void gemm_mfma(
        const __hip_bfloat16* __restrict__ A,
        const __hip_bfloat16* __restrict__ Bt,
        const float* __restrict__ bias,
        const float* __restrict__ res,
        void* __restrict__ Cout,
        int N, int Kd, int lda, int ldb, int ldc,
        size_t sAb, size_t sAh, size_t sBb, size_t sBh, size_t sCz) {
    constexpr int NWR = 4 / NWC;
    constexpr int BM = NWR * MR * 16;
    constexpr int BN = NWC * 64;
    __shared__ __align__(16) __hip_bfloat16 As[BM * 64];
    __shared__ __align__(16) __hip_bfloat16 Bs[BN * 64];
    const char* AsB = (const char*)As;
    const char* BsB = (const char*)Bs;
    int z = blockIdx.z;
    const __hip_bfloat16* Ab = A + (size_t)(z >> 4) * sAb + (size_t)(z & 15) * sAh;
    const __hip_bfloat16* Bb = Bt + (size_t)(z >> 4) * sBb + (size_t)(z & 15) * sBh;
    float* Cf = (float*)Cout + (size_t)z * sCz;
    __hip_bfloat16* Cb = (__hip_bfloat16*)Cout + (size_t)z * sCz;
    int m0 = blockIdx.y * BM, n0 = blockIdx.x * BN;
    int t = threadIdx.x;
    int l = t & 63, w = t >> 6;
    int wr = w / NWC, wc = w % NWC;
    int lr = l & 15, kq = l >> 4;
    int rx = lr & 7;

    f32x4 acc[MR][4] = {};

    for (int k0 = 0; k0 < Kd; k0 += 64) {
#pragma unroll
        for (int i = 0; i < BM / 32; i++) {
            int e = t + i * 256;
            int row = e >> 3, sl = e & 7;
            int kb = sl ^ (row & 7);
            ldsld16(Ab + (size_t)(m0 + row) * lda + (k0 + kb * 8), (void*)(AsB + e * 16));
        }
#pragma unroll
        for (int i = 0; i < BN / 32; i++) {
            int e = t + i * 256;
            int row = e >> 3, sl = e & 7;
            int kb = sl ^ (row & 7);
            int nr = n0 + row; if (nr > N - 1) nr = N - 1;   // tail tile (arf N=129)
            ldsld16(Bb + (size_t)nr * ldb + (k0 + kb * 8), (void*)(BsB + e * 16));
        }
        __syncthreads();
#pragma unroll
        for (int kc = 0; kc < 2; kc++) {
            int sloff = (((kc << 2) + kq) ^ rx) << 4;
            v8bf16 af[MR], bfr[4];
#pragma unroll
            for (int mr = 0; mr < MR; mr++)
                af[mr] = *(const v8bf16*)(AsB + ((wr * (MR * 16) + mr * 16 + lr) << 7) + sloff);
#pragma unroll
            for (int nc = 0; nc < 4; nc++)
                bfr[nc] = *(const v8bf16*)(BsB + ((wc * 64 + nc * 16 + lr) << 7) + sloff);
#pragma unroll
            for (int mr = 0; mr < MR; mr++)
#pragma unroll
                for (int nc = 0; nc < 4; nc++)
                    acc[mr][nc] = __builtin_amdgcn_mfma_f32_16x16x32_bf16(
                        af[mr], bfr[nc], acc[mr][nc], 0, 0, 0);
        }
        __syncthreads();
    }

#pragma unroll
    for (int mr = 0; mr < MR; mr++) {
        int rbase = m0 + wr * (MR * 16) + mr * 16 + kq * 4;
#pragma unroll
        for (int nc = 0; nc < 4; nc++) {
            int col = n0 + wc * 64 + nc * 16 + lr;
            bool okc = col < N;
            float bv = (bias && okc) ? bias[col] : 0.f;
#pragma unroll
            for (int ri = 0; ri < 4; ri++) {
                int r = rbase + ri;
                float val = acc[mr][nc][ri] + bv;
                if (ACT == 1) val = gelu_f(val);
                if (ACT == 2) val = fmaxf(val, 0.f);
                if (RES == 1) val += res[(size_t)r * ldc + col];
                if (RES == 2) val += __bfloat162float(
                        ((const __hip_bfloat16*)res)[(size_t)r * ldc + col]);
                if (okc) {
                    if (OUTBF == 2) {
                        if (col < D_) Cf[(size_t)r * ldc + col] = val;
                        else ((__hip_bfloat16*)res)[(size_t)r * ldc + (col - D_)] =
                                 __float2bfloat16(val);
                    } else if (OUTBF == 1) {
                        Cb[(size_t)r * ldc + col] = __float2bfloat16(val);
                    } else {
                        Cf[(size_t)r * ldc + col] = val;
                    }
                }
            }
        }
    }
}

// ---------------- fused attention, two-pass flash (exp2 space) --------------
// Block = 64 q-rows x one (b,h); wave w owns rows w*16..w*16+15.
// R15 structure: p-phase writes LDS pB only; coalesced a_out stream after PV.
#define FA_AR 0                       // 64*132*2 = 16896 B
#define FA_K  16896                   // 64x64 bf16 = 8192 B
#define FA_V  (16896 + 8192)          // 8192 B
#define FA_P  (16896 + 16384)         // 8192 B (p tile; also initial Q staging)
#define SC2   0.1803368801111244f     // 0.125 * log2(e)
__global__ __launch_bounds__(256) void flash_attn7(
        const __hip_bfloat16* __restrict__ qkv,
        const __hip_bfloat16* __restrict__ vt,
        const __hip_bfloat16* __restrict__ arfb,
        const __hip_bfloat16* __restrict__ gb,
        float* __restrict__ a_out,
        __hip_bfloat16* __restrict__ obuf) {
    __shared__ __align__(16) char lds[16896 + 8192 * 3];
    __hip_bfloat16* arl = (__hip_bfloat16*)(lds + FA_AR);
    char* kB = lds + FA_K;
    char* vB = lds + FA_V;
    char* pB = lds + FA_P;

    int z = blockIdx.y, b = z >> 4, h = z & 15;
    int i0 = blockIdx.x * 64;
    int t = threadIdx.x, l = t & 63, w = t >> 6;
    int lr = l & 15, kq = l >> 4;

    // stage Q (64 rows x 64 d, swizzled) into pB; arf rows into arl
#pragma unroll
    for (int i = 0; i < 2; i++) {
        int e = t + i * 256;
        int row = e >> 3, sl = e & 7;
        int kb = sl ^ (row & 7);
        ldsld16(qkv + (size_t)(b * I_ + i0 + row) * QKVLD + h * DH_ + kb * 8,
                (void*)(pB + e * 16));
    }
    for (int idx = t; idx < 64 * 132; idx += 256) {
        int row = idx / 132, r = idx - row * 132;
        if (r < R_) arl[idx] = arfb[((size_t)z * I_ + i0 + row) * R_ + r];
    }
    __syncthreads();
    v8bf16 qf[2];
#pragma unroll
    for (int kc = 0; kc < 2; kc++)
        qf[kc] = *(const v8bf16*)(pB + ((w * 16 + lr) << 7) + ((((kc << 2) + kq) ^ (lr & 7)) << 4));

    int irow = w * 16 + kq * 4;      // lane's first row within 64
    int ig = i0 + irow;              // global i for ri=0
    float loS[4], hiS[4];
#pragma unroll
    for (int ri = 0; ri < 4; ri++) {
        loS[ri] = __bfloat162float(arl[(irow + ri) * 132 + 0])   * SC2;
        hiS[ri] = __bfloat162float(arl[(irow + ri) * 132 + 128]) * SC2;
    }

    // ---- pass A: per-lane l = sum exp2(s2) --------------------------------
    float l_ln[4] = {0.f, 0.f, 0.f, 0.f};
    for (int jt = 0; jt < 16; jt++) {
        int j0 = jt * 64;
#pragma unroll
        for (int i = 0; i < 2; i++) {
            int e = t + i * 256;
            int row = e >> 3, sl = e & 7;
            int kb = sl ^ (row & 7);
            ldsld16(qkv + (size_t)(b * I_ + j0 + row) * QKVLD + D_ + h * DH_ + kb * 8,
                    (void*)(kB + e * 16));
        }
        __syncthreads();
        f32x4 acc[4] = {};
        __builtin_amdgcn_s_setprio(1);
#pragma unroll
        for (int kc = 0; kc < 2; kc++) {
            int sloff = ((((kc << 2) + kq)) ^ (lr & 7)) << 4;
#pragma unroll
            for (int tt = 0; tt < 4; tt++) {
                v8bf16 kf = *(const v8bf16*)(kB + ((tt * 16 + lr) << 7) + sloff);
                acc[tt] = __builtin_amdgcn_mfma_f32_16x16x32_bf16(qf[kc], kf, acc[tt], 0, 0, 0);
            }
        }
        __builtin_amdgcn_s_setprio(0);
#pragma unroll
        for (int ri = 0; ri < 4; ri++) {
            int i_g = ig + ri;
            float sc[4];
            bool lo_all = (j0 + 63) <= (i_g - 64);
            bool hi_all = j0 >= (i_g + 64);
            if (lo_all || hi_all) {
                float c = lo_all ? loS[ri] : hiS[ri];
#pragma unroll
                for (int tt = 0; tt < 4; tt++) sc[tt] = fmaf(acc[tt][ri], SC2, c);
            } else {
#pragma unroll
                for (int tt = 0; tt < 4; tt++) {
                    int rel = j0 + tt * 16 + lr - i_g;
                    rel = rel < -64 ? -64 : (rel > 64 ? 64 : rel);
                    sc[tt] = (acc[tt][ri] + __bfloat162float(arl[(irow + ri) * 132 + rel + 64])) * SC2;
                }
            }
            l_ln[ri] += exp2f(sc[0]) + exp2f(sc[1]) + exp2f(sc[2]) + exp2f(sc[3]);
        }
        __syncthreads();
    }
    float offb[4];
#pragma unroll
    for (int ri = 0; ri < 4; ri++) {
        float s = l_ln[ri];
#pragma unroll
        for (int off = 1; off < 16; off <<= 1) s += __shfl_xor(s, off, 64);
        offb[ri] = __log2f(s);
    }

    // ---- pass B: p -> pB; PV; coalesced a_out write from pB ---------------
    f32x4 oacc[4] = {};
    for (int jt = 0; jt < 16; jt++) {
        int j0 = jt * 64;
#pragma unroll
        for (int i = 0; i < 2; i++) {
            int e = t + i * 256;
            int row = e >> 3, sl = e & 7;
            int kb = sl ^ (row & 7);
            ldsld16(qkv + (size_t)(b * I_ + j0 + row) * QKVLD + D_ + h * DH_ + kb * 8,
                    (void*)(kB + e * 16));
            ldsld16(vt + ((size_t)z * DH_ + row) * I_ + j0 + kb * 8,
                    (void*)(vB + e * 16));
        }
        __syncthreads();
        f32x4 acc[4] = {};
        __builtin_amdgcn_s_setprio(1);
#pragma unroll
        for (int kc = 0; kc < 2; kc++) {
            int sloff = ((((kc << 2) + kq)) ^ (lr & 7)) << 4;
#pragma unroll
            for (int tt = 0; tt < 4; tt++) {
                v8bf16 kf = *(const v8bf16*)(kB + ((tt * 16 + lr) << 7) + sloff);
                acc[tt] = __builtin_amdgcn_mfma_f32_16x16x32_bf16(qf[kc], kf, acc[tt], 0, 0, 0);
            }
        }
        __builtin_amdgcn_s_setprio(0);
#pragma unroll
        for (int ri = 0; ri < 4; ri++) {
            int i_g = ig + ri;
            int rowl = irow + ri;
            float sc[4];
            bool lo_all = (j0 + 63) <= (i_g - 64);
            bool hi_all = j0 >= (i_g + 64);
            if (lo_all || hi_all) {
                float c = lo_all ? loS[ri] : hiS[ri];
#pragma unroll
                for (int tt = 0; tt < 4; tt++) sc[tt] = fmaf(acc[tt][ri], SC2, c);
            } else {
#pragma unroll
                for (int tt = 0; tt < 4; tt++) {
                    int rel = j0 + tt * 16 + lr - i_g;
                    rel = rel < -64 ? -64 : (rel > 64 ? 64 : rel);
                    sc[tt] = (acc[tt][ri] + __bfloat162float(arl[rowl * 132 + rel + 64])) * SC2;
                }
            }
#pragma unroll
            for (int tt = 0; tt < 4; tt++) {
                float p = exp2f(sc[tt] - offb[ri]);
                *(__hip_bfloat16*)(pB + (rowl << 7) +
                        ((((tt * 2) + (lr >> 3)) ^ (rowl & 7)) << 4) + (lr & 7) * 2) =
                    __float2bfloat16(p);
            }
        }
        __syncthreads();
        __builtin_amdgcn_s_setprio(1);
#pragma unroll
        for (int kc = 0; kc < 2; kc++) {
            int sloff = ((((kc << 2) + kq)) ^ (lr & 7)) << 4;
            v8bf16 pf = *(const v8bf16*)(pB + ((w * 16 + lr) << 7) + sloff);
#pragma unroll
            for (int nc = 0; nc < 4; nc++) {
                v8bf16 vf = *(const v8bf16*)(vB + ((nc * 16 + lr) << 7) + sloff);
                oacc[nc] = __builtin_amdgcn_mfma_f32_16x16x32_bf16(pf, vf, oacc[nc], 0, 0, 0);
            }
        }
        __builtin_amdgcn_s_setprio(0);
        // coalesced a_out write from pB (256B segments per wave-instruction)
        {
            float* gbase = a_out + ((size_t)z * I_ + i0) * I_ + j0;
#pragma unroll
            for (int g = 0; g < 4; g++) {
                int idx = t + g * 256;
                int row = idx >> 4, c4 = (idx & 15) * 4;
                const __hip_bfloat16* ph = (const __hip_bfloat16*)(pB + (row << 7) +
                        (((c4 >> 3) ^ (row & 7)) << 4) + (c4 & 7) * 2);
                f32x4 o4;
                o4[0] = __bfloat162float(ph[0]); o4[1] = __bfloat162float(ph[1]);
                o4[2] = __bfloat162float(ph[2]); o4[3] = __bfloat162float(ph[3]);
                __builtin_nontemporal_store(o4,
                        (f32x4*)(gbase + (size_t)row * I_ + c4));
            }
        }
        __syncthreads();
    }
#pragma unroll
    for (int nc = 0; nc < 4; nc++) {
#pragma unroll
        for (int ri = 0; ri < 4; ri++) {
            int r = i0 + irow + ri;
            size_t oi = ((size_t)(b * I_ + r)) * D_ + h * DH_ + nc * 16 + lr;
            obuf[oi] = __float2bfloat16(oacc[nc][ri] * __bfloat162float(gb[oi]));
        }
    }
}

// ---------------- LayerNorm rows of 1024 (256 thr), INBF/OUTBF --------------
template<int INBF, int OUTBF>
__global__ __launch_bounds__(256) void ln_kernel(const void* __restrict__ in,
        void* __restrict__ out, const float* __restrict__ gw,
        const float* __restrict__ bw) {
    __shared__ float shs[4], shq[4];
    int row = blockIdx.x;
    int t = threadIdx.x;
    float e0, e1, e2, e3;
    if (INBF) {
        uint2 u = reinterpret_cast<const uint2*>(
                (const __hip_bfloat16*)in + (size_t)row * D_)[t];
        const __hip_bfloat16* hp = (const __hip_bfloat16*)&u;
        e0 = __bfloat162float(hp[0]); e1 = __bfloat162float(hp[1]);
        e2 = __bfloat162float(hp[2]); e3 = __bfloat162float(hp[3]);
    } else {
        float4 v = reinterpret_cast<const float4*>(
                (const float*)in + (size_t)row * D_)[t];
        e0 = v.x; e1 = v.y; e2 = v.z; e3 = v.w;
    }
    float s = e0 + e1 + e2 + e3;
#pragma unroll
    for (int off = 32; off > 0; off >>= 1) s += __shfl_down(s, off, 64);
    if ((t & 63) == 0) shs[t >> 6] = s;
    __syncthreads();
    float mean = (shs[0] + shs[1] + shs[2] + shs[3]) * (1.0f / D_);
    float d0 = e0 - mean, d1 = e1 - mean, d2 = e2 - mean, d3 = e3 - mean;
    float q = d0 * d0 + d1 * d1 + d2 * d2 + d3 * d3;
#pragma unroll
    for (int off = 32; off > 0; off >>= 1) q += __shfl_down(q, off, 64);
    if ((t & 63) == 0) shq[t >> 6] = q;
    __syncthreads();
    float var = (shq[0] + shq[1] + shq[2] + shq[3]) * (1.0f / D_);
    float rstd = rsqrtf(var + 1e-5f);
    float4 g4 = reinterpret_cast<const float4*>(gw)[t];
    float4 b4 = reinterpret_cast<const float4*>(bw)[t];
    float o0 = d0 * rstd * g4.x + b4.x;
    float o1 = d1 * rstd * g4.y + b4.y;
    float o2 = d2 * rstd * g4.z + b4.z;
    float o3 = d3 * rstd * g4.w + b4.w;
    if (OUTBF) {
        union { __hip_bfloat16 h[4]; uint2 u; } pk;
        pk.h[0] = __float2bfloat16(o0); pk.h[1] = __float2bfloat16(o1);
        pk.h[2] = __float2bfloat16(o2); pk.h[3] = __float2bfloat16(o3);
        reinterpret_cast<uint2*>((__hip_bfloat16*)out + (size_t)row * D_)[t] = pk.u;
    } else {
        float4 o; o.x = o0; o.y = o1; o.z = o2; o.w = o3;
        reinterpret_cast<float4*>((float*)out + (size_t)row * D_)[t] = o;
    }
}

extern "C" void kernel_launch(void* const* d_in, const int* in_sizes, int n_in,
                              void* d_out, int out_size, void* d_ws, size_t ws_size,
                              hipStream_t stream) {
    const float* x      = (const float*)d_in[0];
    const float* jin    = (const float*)d_in[1];
    const float* ln1_g  = (const float*)d_in[2];
    const float* ln1_b  = (const float*)d_in[3];
    const float* Wv_w   = (const float*)d_in[4];
    const float* Wv_b   = (const float*)d_in[5];
    const float* Wg_w   = (const float*)d_in[6];
    const float* Wg_b   = (const float*)d_in[7];
    const float* lnv_g  = (const float*)d_in[8];
    const float* lnv_b  = (const float*)d_in[9];
    const float* Wq1_w  = (const float*)d_in[10];
    const float* Wq1_b  = (const float*)d_in[11];
    const float* Wk_w   = (const float*)d_in[12];
    const float* Wk_b   = (const float*)d_in[13];
    const float* Wq2_w  = (const float*)d_in[14];
    const float* Wq2_b  = (const float*)d_in[15];
    const float* rel    = (const float*)d_in[16];
    const float* Wo_w   = (const float*)d_in[17];
    const float* Wo_b   = (const float*)d_in[18];
    const float* ln2_g  = (const float*)d_in[19];
    const float* ln2_b  = (const float*)d_in[20];
    const float* ff1_w  = (const float*)d_in[21];
    const float* ff1_b  = (const float*)d_in[22];
    const float* ff2_w  = (const float*)d_in[23];
    const float* ff2_b  = (const float*)d_in[24];
    // d_in[25] = indices: computed analytically on device

    float* out0  = (float*)d_out;
    float* a_out = out0 + (size_t)B_ * I_ * D_;    // [B,H,I,J]

    char* wsb = (char*)d_ws;
    const size_t MB = 1u << 20;
    // persistent bf16 transposed weights [0,28MB)
    __hip_bfloat16* wvwgT= (__hip_bfloat16*)(wsb + 0 * MB);   // [2048,1024] 4MB
    __hip_bfloat16* qkvT = (__hip_bfloat16*)(wsb + 4 * MB);   // [3072,1024] 6MB
    __hip_bfloat16* WoT  = (__hip_bfloat16*)(wsb + 10 * MB);
    __hip_bfloat16* ff1T = (__hip_bfloat16*)(wsb + 12 * MB);  // [4096,1024] 8MB
    __hip_bfloat16* ff2T = (__hip_bfloat16*)(wsb + 20 * MB);  // [1024,4096] 8MB
    // activations, slot-reused along the timeline
    __hip_bfloat16* jbf  = (__hip_bfloat16*)(wsb + 28 * MB);  // dead after qkv GEMM
    __hip_bfloat16* qkv  = (__hip_bfloat16*)(wsb + 32 * MB);  // [2048,3072] 12MB, live->flash
    __hip_bfloat16* relb = (__hip_bfloat16*)(wsb + 44 * MB);  // 0.26MB, dead after arf
    __hip_bfloat16* arfb = (__hip_bfloat16*)(wsb + 45 * MB);  // 8.06MB, live->flash
    __hip_bfloat16* gbuf = (__hip_bfloat16*)(wsb + 54 * MB);  // 4MB, live->flash
    float*          vbuf = (float*)        (wsb + 58 * MB);   // 8MB f32, dead after vtrans
    __hip_bfloat16* xnb  = (__hip_bfloat16*)(wsb + 28 * MB);  // reuse jbf (dead after WvWg)
    __hip_bfloat16* vt   = (__hip_bfloat16*)(wsb + 28 * MB);  // reuse xnb, live->flash
    __hip_bfloat16* obuf = (__hip_bfloat16*)(wsb + 58 * MB);  // reuse vbuf (dead)
    __hip_bfloat16* x1b  = (__hip_bfloat16*)(wsb + 32 * MB);  // reuse qkv (dead), 4MB bf16
    __hip_bfloat16* x1nb = (__hip_bfloat16*)(wsb + 40 * MB);  // reuse qkv tail (dead)
    __hip_bfloat16* hbuf = (__hip_bfloat16*)(wsb + 44 * MB);  // 16MB, 44-60 (all dead)
    float*          bias3= (float*)        (wsb + 66 * MB);   // [3072] f32 concat
    float*          bias2= (float*)        (wsb + 66 * MB + 16384);  // [2048] f32 concat
    float*          stats= (float*)        (wsb + 67 * MB);   // [2048][2] f32 lnv stats

    dim3 blk(256);

    // prologue: 4 dispatches
    cvt_bf16<<<2048, blk, 0, stream>>>(jin, jbf, (MROWS * D_) / 4);
    cvt_rel_bias<<<134, blk, 0, stream>>>(rel, relb,
        Wq1_b, Wk_b, Wq2_b, Wv_b, Wg_b, bias3, bias2);
    wtrans6<<<dim3(16, 16, 6), blk, 0, stream>>>(
        Wq1_w, Wk_w, Wq2_w, Wv_w, Wg_w, Wo_w,
        qkvT, qkvT + 1024*1024, qkvT + 2048*1024,
        wvwgT, wvwgT + 1024*1024, WoT);
    wtrans_ff<<<dim3(64, 16, 2), blk, 0, stream>>>(ff1_w, ff2_w, ff1T, ff2T);

    // merged q1|k|q2 projection: 64x128 tiles, grid 24x32 = 768 blocks (even)
    gemm_mfma<2, 2, 0, 0, 1><<<dim3(24, 32, 1), blk, 0, stream>>>(
        jbf, qkvT, bias3, nullptr, qkv, QKVLD, D_, D_, D_, QKVLD, 0, 0, 0, 0, 0);
    // arf[bh,i,r] = q2 . rel  (A = qkv q2 third, stride 3072)
    gemm_mfma<4, 2, 0, 0, 1><<<dim3(2, 8, 32), blk, 0, stream>>>(
        qkv + 2 * D_, relb, nullptr, nullptr, arfb,
        R_, DH_, QKVLD, D_, R_,
        (size_t)I_ * QKVLD, (size_t)DH_, 0, (size_t)DH_, (size_t)I_ * R_);

    // value/gate: merged Wv|Wg GEMM, split epilogue (f32 vbuf | bf16 gbuf)
    ln_kernel<0, 1><<<MROWS, blk, 0, stream>>>(x, xnb, ln1_g, ln1_b);
    gemm_mfma<2, 2, 1, 0, 2><<<dim3(16, 32, 1), blk, 0, stream>>>(
        xnb, wvwgT, bias2, (const float*)gbuf, vbuf, 2 * D_, D_, D_, D_, D_, 0, 0, 0, 0, 0);
    rowstats<<<MROWS, blk, 0, stream>>>(vbuf, stats);
    vtrans_ln<<<dim3(16, 32), blk, 0, stream>>>(vbuf, stats, lnv_g, lnv_b, vt);

    // fused attention: two-pass flash, coalesced a_out write
    flash_attn7<<<dim3(16, 32), blk, 0, stream>>>(qkv, vt, arfb, gbuf, a_out, obuf);

    // output projection + residual (bf16 x1), FF block
    gemm_mfma<2, 1, 0, 1, 1><<<dim3(16, 16, 1), blk, 0, stream>>>(
        obuf, WoT, Wo_b, x, x1b, D_, D_, D_, D_, D_, 0, 0, 0, 0, 0);
    ln_kernel<1, 1><<<MROWS, blk, 0, stream>>>(x1b, x1nb, ln2_g, ln2_b);
    gemm_mfma<4, 2, 2, 0, 1><<<dim3(32, 16, 1), blk, 0, stream>>>(
        x1nb, ff1T, ff1_b, nullptr, hbuf, FF_, D_, D_, D_, FF_, 0, 0, 0, 0, 0);
    gemm_mfma<2, 1, 0, 2, 0><<<dim3(16, 16, 1), blk, 0, stream>>>(
        hbuf, ff2T, ff2_b, (const float*)x1b, out0, D_, FF_, FF_, FF_, D_, 0, 0, 0, 0, 0);
}